// Round 4
// baseline (12352.850 us; speedup 1.0000x reference)
//
#include <hip/hip_runtime.h>
#include <hip/hip_bf16.h>

// B=256, T=64, F=32, ENC_U=256, DEC_U=512, VOCAB=2048, EMB=512, EPS=1e-3
// ALL float arrays are FLOAT32 storage (per the reference's jnp.float32).
// ALL intermediates live inside d_out ([16384 rows][2048 cols] fp32, 128 MiB):
//   cols    0..511 , rows 0..16383 : enc_out -> overwritten by h (same owner block)
//   cols  512..1023, rows 0..6143  : EMBX [2048][1536] mapped (E>>9 -> row, 512+(E&511))
//   cols 1024..2047, rows 0..8191  : keysT [256][512][64] mapped (K>>10 -> row, 1024+(K&1023))
// d_ws is not used at all.
static constexpr float INV_SQ = 0.99950037468777319f;  // 1/sqrt(1+1e-3)

typedef __hip_bfloat16 bf16;
__device__ __forceinline__ float bf2f(bf16 x) { return __bfloat162float(x); }
__device__ __forceinline__ float sigm(float x) { return 1.0f / (1.0f + __expf(-x)); }

// ---------------------------------------------------------------------------
// Encoder: persistent bidirectional GRU. block = (dir, b-pair). 256 blocks.
// ---------------------------------------------------------------------------
__global__ __launch_bounds__(256)
void enc_gru(const float* __restrict__ x,
             const float* __restrict__ g_e, const float* __restrict__ b_e,
             const float* __restrict__ WxF, const float* __restrict__ WhF,
             const float* __restrict__ bxF, const float* __restrict__ bhF,
             const float* __restrict__ WxB, const float* __restrict__ WhB,
             const float* __restrict__ bxB, const float* __restrict__ bhB,
             float* __restrict__ out)
{
    const int u   = threadIdx.x;
    const int dir = blockIdx.x & 1;
    const int b0  = (blockIdx.x >> 1) * 2;

    const float* Wx = dir ? WxB : WxF;
    const float* Wh = dir ? WhB : WhF;
    const float* bx = dir ? bxB : bxF;
    const float* bh = dir ? bhB : bhF;

    __shared__ float hs[2][256];
    __shared__ float xs[2][32];

    hs[0][u] = 0.0f; hs[1][u] = 0.0f;
    const float bxz = bx[u], bxr = bx[256 + u], bxh = bx[512 + u];
    const float bhz = bh[u], bhr = bh[256 + u], bhn = bh[512 + u];

    for (int t = 0; t < 64; ++t) {
        const int ts = dir ? (63 - t) : t;
        if (u < 64) {
            const int f = u & 31, bs = u >> 5;
            xs[bs][f] = x[((b0 + bs) * 64 + ts) * 32 + f] * (g_e[f] * INV_SQ) + b_e[f];
        }
        __syncthreads();

        float az0 = bxz, ar0 = bxr, ah0 = bxh;
        float az1 = bxz, ar1 = bxr, ah1 = bxh;
        #pragma unroll 8
        for (int f = 0; f < 32; ++f) {
            const float x0 = xs[0][f], x1 = xs[1][f];
            const float wz = Wx[f * 768 + u];
            const float wr = Wx[f * 768 + 256 + u];
            const float wn = Wx[f * 768 + 512 + u];
            az0 += x0 * wz; ar0 += x0 * wr; ah0 += x0 * wn;
            az1 += x1 * wz; ar1 += x1 * wr; ah1 += x1 * wn;
        }
        float gz0 = bhz, gr0 = bhr, gn0 = bhn;
        float gz1 = bhz, gr1 = bhr, gn1 = bhn;
        #pragma unroll 4
        for (int up = 0; up < 256; ++up) {
            const float h0 = hs[0][up], h1 = hs[1][up];
            const float wz = Wh[up * 768 + u];
            const float wr = Wh[up * 768 + 256 + u];
            const float wn = Wh[up * 768 + 512 + u];
            gz0 += h0 * wz; gr0 += h0 * wr; gn0 += h0 * wn;
            gz1 += h1 * wz; gr1 += h1 * wr; gn1 += h1 * wn;
        }
        const float hp0 = hs[0][u], hp1 = hs[1][u];
        const float z0 = sigm(az0 + gz0), r0 = sigm(ar0 + gr0);
        const float n0 = tanhf(ah0 + r0 * gn0);
        const float hn0 = z0 * hp0 + (1.0f - z0) * n0;
        const float z1 = sigm(az1 + gz1), r1 = sigm(ar1 + gr1);
        const float n1 = tanhf(ah1 + r1 * gn1);
        const float hn1 = z1 * hp1 + (1.0f - z1) * n1;
        __syncthreads();
        hs[0][u] = hn0; hs[1][u] = hn1;
        out[((b0    ) * 64 + ts) * 2048 + dir * 256 + u] = hn0;
        out[((b0 + 1) * 64 + ts) * 2048 + dir * 256 + u] = hn1;
        __syncthreads();
    }
}

// ---------------------------------------------------------------------------
// keys = enc_out @ W1 + b1, written transposed into the keysT region.
// Block = 16 enc rows (one batch since 16 | 64). 1024 blocks.
// ---------------------------------------------------------------------------
__global__ __launch_bounds__(256)
void keys_k(float* __restrict__ out, const float* __restrict__ W1,
            const float* __restrict__ b1)
{
    __shared__ __align__(16) float As[16 * 512];
    const int tid = threadIdx.x;
    const int r0  = blockIdx.x * 16;

    #pragma unroll
    for (int i = 0; i < 32; ++i) {
        const int idx = tid + i * 256;
        const int r = idx >> 9, k = idx & 511;
        As[idx] = out[(r0 + r) * 2048 + k];
    }
    __syncthreads();

    const int bb = r0 >> 6;
    const int n1 = tid, n2 = tid + 256;
    float acc1[16], acc2[16];
    const float bb1 = b1[n1], bb2 = b1[n2];
    #pragma unroll
    for (int r = 0; r < 16; ++r) { acc1[r] = bb1; acc2[r] = bb2; }

    for (int k = 0; k < 512; k += 4) {
        float w1[4], w2[4];
        #pragma unroll
        for (int kk = 0; kk < 4; ++kk) {
            w1[kk] = W1[(k + kk) * 512 + n1];
            w2[kk] = W1[(k + kk) * 512 + n2];
        }
        #pragma unroll
        for (int r = 0; r < 16; ++r) {
            const float4 a = *reinterpret_cast<const float4*>(&As[r * 512 + k]);
            acc1[r] += a.x * w1[0] + a.y * w1[1] + a.z * w1[2] + a.w * w1[3];
            acc2[r] += a.x * w2[0] + a.y * w2[1] + a.z * w2[2] + a.w * w2[3];
        }
    }

    // keysT flat K = bb*32768 + n*64 + tt -> out[(K>>10)*2048 + 1024 + (K&1023)]
    #pragma unroll
    for (int r = 0; r < 16; ++r) {
        const int tt = (r0 + r) & 63;
        const int a1 = (bb * 32 + (n1 >> 4)) * 2048 + 1024 + ((n1 & 15) << 6) + tt;
        const int a2 = (bb * 32 + (n2 >> 4)) * 2048 + 1024 + ((n2 & 15) << 6) + tt;
        out[a1] = acc1[r];
        out[a2] = acc2[r];
    }
}

// ---------------------------------------------------------------------------
// EMBX[v,n] = ((emb[v]*g2+beta2) @ Wxd_bot)[n] + (beta1 @ Wxd_top)[n] + bx_d[n]
// grid (128, 3): 16 emb rows x 512 cols.
// ---------------------------------------------------------------------------
__global__ __launch_bounds__(256)
void embx_k(float* __restrict__ out, const float* __restrict__ emb,
            const float* __restrict__ g, const float* __restrict__ be,
            const float* __restrict__ Wxd, const float* __restrict__ bxd)
{
    __shared__ __align__(16) float As[16 * 512];
    const int tid = threadIdx.x;
    const int r0  = blockIdx.x * 16;
    const int n0  = blockIdx.y * 512;

    #pragma unroll
    for (int i = 0; i < 32; ++i) {
        const int idx = tid + i * 256;
        const int r = idx >> 9, k = idx & 511;
        As[idx] = emb[(r0 + r) * 512 + k] * (g[512 + k] * INV_SQ) + be[512 + k];
    }
    __syncthreads();

    const int n1 = n0 + tid, n2 = n0 + tid + 256;
    float cv1 = bxd[n1], cv2 = bxd[n2];
    for (int i = 0; i < 512; ++i) {
        const float bi = be[i];
        cv1 += bi * Wxd[i * 1536 + n1];
        cv2 += bi * Wxd[i * 1536 + n2];
    }

    float acc1[16], acc2[16];
    #pragma unroll
    for (int r = 0; r < 16; ++r) { acc1[r] = cv1; acc2[r] = cv2; }

    for (int k = 0; k < 512; k += 4) {
        float w1[4], w2[4];
        #pragma unroll
        for (int kk = 0; kk < 4; ++kk) {
            w1[kk] = Wxd[(512 + k + kk) * 1536 + n1];
            w2[kk] = Wxd[(512 + k + kk) * 1536 + n2];
        }
        #pragma unroll
        for (int r = 0; r < 16; ++r) {
            const float4 a = *reinterpret_cast<const float4*>(&As[r * 512 + k]);
            acc1[r] += a.x * w1[0] + a.y * w1[1] + a.z * w1[2] + a.w * w1[3];
            acc2[r] += a.x * w2[0] + a.y * w2[1] + a.z * w2[2] + a.w * w2[3];
        }
    }

    #pragma unroll
    for (int r = 0; r < 16; ++r) {
        const int E1 = (r0 + r) * 1536 + n1;
        const int E2 = (r0 + r) * 1536 + n2;
        out[(E1 >> 9) * 2048 + 512 + (E1 & 511)] = acc1[r];
        out[(E2 >> 9) * 2048 + 512 + (E2 & 511)] = acc2[r];
    }
}

// ---------------------------------------------------------------------------
// Decoder: persistent per-batch. 256 blocks. Stages its enc rows into LDS
// (bf16), then overwrites the same out rows (cols 0..511) with h.
// ---------------------------------------------------------------------------
__global__ __launch_bounds__(256)
void decoder(float* __restrict__ out,
             const float* __restrict__ Wxd,   // rows 0..511 (Wxd_top) used in-loop
             const float* __restrict__ g1,    // bn_d_gamma[0..511]
             const float* __restrict__ W2, const float* __restrict__ b2,
             const float* __restrict__ V, const float* __restrict__ bV,
             const float* __restrict__ bh_d, const int* __restrict__ targ)
{
    const int b = blockIdx.x, tid = threadIdx.x;
    const int c0 = tid * 2, c1 = c0 + 1;

    __shared__ bf16  encL[64][512];               // 64 KiB
    __shared__ float hs[512], qs[512], cg[512], Vl[512], g1l[512];
    __shared__ float part[4][64], sc[64], wv[64];

    float* erow = out + b * 64 * 2048;
    for (int i = tid; i < 32768; i += 256)
        encL[i >> 9][i & 511] = __float2bfloat16(erow[((i >> 9) << 11) + (i & 511)]);
    // dec_h0 = concat(forward final (t=63, cols<256), backward final (t=0, cols>=256))
    hs[c0] = (c0 < 256) ? erow[63 * 2048 + c0] : erow[c0];
    hs[c1] = (c1 < 256) ? erow[63 * 2048 + c1] : erow[c1];
    Vl[c0]  = V[c0];            Vl[c1]  = V[c1];
    g1l[c0] = g1[c0] * INV_SQ;  g1l[c1] = g1[c1] * INV_SQ;
    const float bVv  = bV[0];
    const float b2a  = b2[c0],          b2b  = b2[c1];
    const float bhz0 = bh_d[c0],        bhz1 = bh_d[c1];
    const float bhr0 = bh_d[512 + c0],  bhr1 = bh_d[512 + c1];
    const float bhn0 = bh_d[1024 + c0], bhn1 = bh_d[1024 + c1];
    const float2* W2v  = reinterpret_cast<const float2*>(W2);
    const float2* Wxdv = reinterpret_cast<const float2*>(Wxd);
    __syncthreads();

    for (int t = 0; t < 64; ++t) {
        // ---- q = hs @ W2 + b2 (cols c0,c1 adjacent -> float2 loads)
        {
            float a0 = b2a, a1 = b2b;
            #pragma unroll 4
            for (int i = 0; i < 512; ++i) {
                const float hv = hs[i];
                const float2 w = W2v[i * 256 + tid];
                a0 += hv * w.x; a1 += hv * w.y;
            }
            qs[c0] = a0; qs[c1] = a1;
        }
        __syncthreads();
        // ---- score partials from keysT region: thread = (quarter tq, time tt)
        {
            const int tt = tid & 63, tq = tid >> 6;
            float p = 0.0f;
            for (int a = tq * 8; a < tq * 8 + 8; ++a) {
                const float* kr = out + b * 65536 + a * 2048 + 1024 + tt;
                #pragma unroll
                for (int c = 0; c < 16; ++c) {
                    const int n = a * 16 + c;
                    p += tanhf(kr[c << 6] + qs[n]) * Vl[n];
                }
            }
            part[tq][tt] = p;
        }
        __syncthreads();
        if (tid < 64)
            sc[tid] = part[0][tid] + part[1][tid] + part[2][tid] + part[3][tid] + bVv;
        __syncthreads();
        if (tid < 64) {
            float m = -1e30f;
            for (int j = 0; j < 64; ++j) m = fmaxf(m, sc[j]);
            wv[tid] = __expf(sc[tid] - m);
        }
        __syncthreads();
        float s = 0.0f;
        for (int j = 0; j < 64; ++j) s += wv[j];
        const float inv = 1.0f / s;
        // ---- cg = ctx * g1 * INV_SQ
        {
            float a0 = 0.0f, a1 = 0.0f;
            #pragma unroll 4
            for (int j = 0; j < 64; ++j) {
                const float wj = wv[j];
                a0 += wj * bf2f(encL[j][c0]);
                a1 += wj * bf2f(encL[j][c1]);
            }
            cg[c0] = a0 * inv * g1l[c0];
            cg[c1] = a1 * inv * g1l[c1];
        }
        __syncthreads();
        // ---- xp = EMBX[tok] + cg @ Wxd_top ; gates (h_prev = 0) -> h
        const int tok = targ[b * 64 + t];
        const float* e0 = out + (tok * 3    ) * 2048 + 512;
        const float* e1 = out + (tok * 3 + 1) * 2048 + 512;
        const float* e2 = out + (tok * 3 + 2) * 2048 + 512;
        const float2 ez = *reinterpret_cast<const float2*>(e0 + c0);
        const float2 er = *reinterpret_cast<const float2*>(e1 + c0);
        const float2 eh = *reinterpret_cast<const float2*>(e2 + c0);
        float xz0 = ez.x, xz1 = ez.y;
        float xr0 = er.x, xr1 = er.y;
        float xh0 = eh.x, xh1 = eh.y;
        #pragma unroll 2
        for (int u = 0; u < 512; ++u) {
            const float cu = cg[u];
            const float2 wz = Wxdv[u * 768 + tid];
            const float2 wr = Wxdv[u * 768 + 256 + tid];
            const float2 wn = Wxdv[u * 768 + 512 + tid];
            xz0 += cu * wz.x; xz1 += cu * wz.y;
            xr0 += cu * wr.x; xr1 += cu * wr.y;
            xh0 += cu * wn.x; xh1 += cu * wn.y;
        }
        const float z0 = sigm(xz0 + bhz0), r0 = sigm(xr0 + bhr0);
        const float h0 = (1.0f - z0) * tanhf(xh0 + r0 * bhn0);
        const float z1 = sigm(xz1 + bhz1), r1 = sigm(xr1 + bhr1);
        const float h1 = (1.0f - z1) * tanhf(xh1 + r1 * bhn1);
        hs[c0] = h0; hs[c1] = h1;
        erow[t * 2048 + c0] = h0;
        erow[t * 2048 + c1] = h1;
        __syncthreads();
    }
}

// ---------------------------------------------------------------------------
// logits = h @ Wfc + bfc, in place: block owns 16 FULL out rows.
// ---------------------------------------------------------------------------
__global__ __launch_bounds__(256)
void logits_k(float* __restrict__ out, const float* __restrict__ Wfc,
              const float* __restrict__ bfc)
{
    __shared__ __align__(16) float hsL[16 * 512];
    const int tid = threadIdx.x;
    const int r0  = blockIdx.x * 16;

    #pragma unroll
    for (int i = 0; i < 32; ++i) {
        const int idx = tid + i * 256;
        const int r = idx >> 9, k = idx & 511;
        hsL[idx] = out[(r0 + r) * 2048 + k];
    }
    __syncthreads();  // all reads of own rows complete before any write below

    for (int half = 0; half < 2; ++half) {
        const int cb = half * 1024 + tid;     // cols cb, cb+256, cb+512, cb+768
        float acc[16][4];
        #pragma unroll
        for (int r = 0; r < 16; ++r)
            #pragma unroll
            for (int j = 0; j < 4; ++j) acc[r][j] = 0.0f;

        for (int k = 0; k < 512; k += 4) {
            float w[4][4];
            #pragma unroll
            for (int kk = 0; kk < 4; ++kk)
                #pragma unroll
                for (int j = 0; j < 4; ++j)
                    w[kk][j] = Wfc[(k + kk) * 2048 + cb + (j << 8)];
            #pragma unroll
            for (int r = 0; r < 16; ++r) {
                const float4 a = *reinterpret_cast<const float4*>(&hsL[r * 512 + k]);
                #pragma unroll
                for (int j = 0; j < 4; ++j)
                    acc[r][j] += a.x * w[0][j] + a.y * w[1][j] + a.z * w[2][j] + a.w * w[3][j];
            }
        }
        float bb[4];
        #pragma unroll
        for (int j = 0; j < 4; ++j) bb[j] = bfc[cb + (j << 8)];
        #pragma unroll
        for (int r = 0; r < 16; ++r)
            #pragma unroll
            for (int j = 0; j < 4; ++j)
                out[(r0 + r) * 2048 + cb + (j << 8)] = acc[r][j] + bb[j];
    }
}

// ---------------------------------------------------------------------------
extern "C" void kernel_launch(void* const* d_in, const int* in_sizes, int n_in,
                              void* d_out, int out_size, void* d_ws, size_t ws_size,
                              hipStream_t stream) {
    (void)in_sizes; (void)n_in; (void)out_size; (void)d_ws; (void)ws_size;
    const float* enc_input = (const float*)d_in[0];
    const float* bn_e_g    = (const float*)d_in[1];
    const float* bn_e_b    = (const float*)d_in[2];
    const float* Wx_f      = (const float*)d_in[3];
    const float* Wh_f      = (const float*)d_in[4];
    const float* bx_f      = (const float*)d_in[5];
    const float* bh_f      = (const float*)d_in[6];
    const float* Wx_b      = (const float*)d_in[7];
    const float* Wh_b      = (const float*)d_in[8];
    const float* bx_b      = (const float*)d_in[9];
    const float* bh_b      = (const float*)d_in[10];
    const float* W1        = (const float*)d_in[11];
    const float* b1        = (const float*)d_in[12];
    const float* W2        = (const float*)d_in[13];
    const float* b2        = (const float*)d_in[14];
    const float* V         = (const float*)d_in[15];
    const float* bV        = (const float*)d_in[16];
    const float* emb       = (const float*)d_in[17];
    const float* bn_d_g    = (const float*)d_in[18];
    const float* bn_d_b    = (const float*)d_in[19];
    const float* Wx_d      = (const float*)d_in[20];
    // d_in[21] = Wh_d unused (decoder GRU runs with h_prev = 0)
    const float* bx_d      = (const float*)d_in[22];
    const float* bh_d      = (const float*)d_in[23];
    const float* Wfc       = (const float*)d_in[24];
    const float* bfc       = (const float*)d_in[25];
    const int*   targ      = (const int*)d_in[26];

    float* out = (float*)d_out;

    // 1. encoder -> enc slots (cols 0..511)
    enc_gru<<<dim3(256), dim3(256), 0, stream>>>(
        enc_input, bn_e_g, bn_e_b, Wx_f, Wh_f, bx_f, bh_f,
        Wx_b, Wh_b, bx_b, bh_b, out);
    // 2. attention keys -> keysT region (cols 1024..2047, rows 0..8191)
    keys_k<<<dim3(1024), dim3(256), 0, stream>>>(out, W1, b1);
    // 3. token table -> EMBX region (cols 512..1023, rows 0..6143)
    embx_k<<<dim3(128, 3), dim3(256), 0, stream>>>(out, emb, bn_d_g, bn_d_b, Wx_d, bx_d);
    // 4. decoder recurrence: h overwrites enc slots (own rows only)
    decoder<<<dim3(256), dim3(256), 0, stream>>>(
        out, Wx_d, bn_d_g, W2, b2, V, bV, bh_d, targ);
    // 5. logits in place: each block owns 16 full rows
    logits_k<<<dim3(1024), dim3(256), 0, stream>>>(out, Wfc, bfc);
}

// Round 5
// 3587.923 us; speedup vs baseline: 3.4429x; 3.4429x over previous
//
#include <hip/hip_runtime.h>
#include <hip/hip_bf16.h>

// B=256, T=64, F=32, ENC_U=256, DEC_U=512, VOCAB=2048, EMB=512, EPS=1e-3
// Float inputs/outputs are FLOAT32 storage. All intermediates live inside
// d_out ([16384 rows][2048 fp32 cols], 128 MiB). Region map (fp32 cols):
//   cols    0..511 , rows 0..16383 : enc_out -> overwritten by h (same owner block)
//   cols 1024..2047, rows 0..8191  : keysT [256][512][64] fp32 (K>>10 -> row, 1024+(K&1023))
//   cols 1024..1791, rows 8192..10239 : EMBX bf16 [2048][1536], token v -> row 8192+v
//   cols 1024..2047, rows 10240..10367: W2p  bf16 packed [k8][c][8]
//   cols 1024..2047, rows 10496..10879: Wxdp bf16 packed [g][u8][c][8]
// d_ws is not used at all.
static constexpr float INV_SQ = 0.99950037468777319f;  // 1/sqrt(1+1e-3)

typedef __hip_bfloat16 bf16;
typedef __attribute__((ext_vector_type(8))) unsigned short us8;
__device__ __forceinline__ float bf2f(bf16 x) { return __bfloat162float(x); }
__device__ __forceinline__ float us2f(unsigned short u) {
    union { unsigned int i; float f; } cv; cv.i = ((unsigned int)u) << 16; return cv.f;
}
__device__ __forceinline__ float sigm(float x) { return 1.0f / (1.0f + __expf(-x)); }

// ---------------------------------------------------------------------------
// Encoder: persistent bidirectional GRU. block = (dir, b-pair). 256 blocks.
// ---------------------------------------------------------------------------
__global__ __launch_bounds__(256)
void enc_gru(const float* __restrict__ x,
             const float* __restrict__ g_e, const float* __restrict__ b_e,
             const float* __restrict__ WxF, const float* __restrict__ WhF,
             const float* __restrict__ bxF, const float* __restrict__ bhF,
             const float* __restrict__ WxB, const float* __restrict__ WhB,
             const float* __restrict__ bxB, const float* __restrict__ bhB,
             float* __restrict__ out)
{
    const int u   = threadIdx.x;
    const int dir = blockIdx.x & 1;
    const int b0  = (blockIdx.x >> 1) * 2;

    const float* Wx = dir ? WxB : WxF;
    const float* Wh = dir ? WhB : WhF;
    const float* bx = dir ? bxB : bxF;
    const float* bh = dir ? bhB : bhF;

    __shared__ float hs[2][256];
    __shared__ float xs[2][32];

    hs[0][u] = 0.0f; hs[1][u] = 0.0f;
    const float bxz = bx[u], bxr = bx[256 + u], bxh = bx[512 + u];
    const float bhz = bh[u], bhr = bh[256 + u], bhn = bh[512 + u];

    for (int t = 0; t < 64; ++t) {
        const int ts = dir ? (63 - t) : t;
        if (u < 64) {
            const int f = u & 31, bs = u >> 5;
            xs[bs][f] = x[((b0 + bs) * 64 + ts) * 32 + f] * (g_e[f] * INV_SQ) + b_e[f];
        }
        __syncthreads();

        float az0 = bxz, ar0 = bxr, ah0 = bxh;
        float az1 = bxz, ar1 = bxr, ah1 = bxh;
        #pragma unroll 8
        for (int f = 0; f < 32; ++f) {
            const float x0 = xs[0][f], x1 = xs[1][f];
            const float wz = Wx[f * 768 + u];
            const float wr = Wx[f * 768 + 256 + u];
            const float wn = Wx[f * 768 + 512 + u];
            az0 += x0 * wz; ar0 += x0 * wr; ah0 += x0 * wn;
            az1 += x1 * wz; ar1 += x1 * wr; ah1 += x1 * wn;
        }
        float gz0 = bhz, gr0 = bhr, gn0 = bhn;
        float gz1 = bhz, gr1 = bhr, gn1 = bhn;
        #pragma unroll 4
        for (int up = 0; up < 256; ++up) {
            const float h0 = hs[0][up], h1 = hs[1][up];
            const float wz = Wh[up * 768 + u];
            const float wr = Wh[up * 768 + 256 + u];
            const float wn = Wh[up * 768 + 512 + u];
            gz0 += h0 * wz; gr0 += h0 * wr; gn0 += h0 * wn;
            gz1 += h1 * wz; gr1 += h1 * wr; gn1 += h1 * wn;
        }
        const float hp0 = hs[0][u], hp1 = hs[1][u];
        const float z0 = sigm(az0 + gz0), r0 = sigm(ar0 + gr0);
        const float n0 = tanhf(ah0 + r0 * gn0);
        const float hn0 = z0 * hp0 + (1.0f - z0) * n0;
        const float z1 = sigm(az1 + gz1), r1 = sigm(ar1 + gr1);
        const float n1 = tanhf(ah1 + r1 * gn1);
        const float hn1 = z1 * hp1 + (1.0f - z1) * n1;
        __syncthreads();
        hs[0][u] = hn0; hs[1][u] = hn1;
        out[((b0    ) * 64 + ts) * 2048 + dir * 256 + u] = hn0;
        out[((b0 + 1) * 64 + ts) * 2048 + dir * 256 + u] = hn1;
        __syncthreads();
    }
}

// ---------------------------------------------------------------------------
// keys = enc_out @ W1 + b1, written transposed into the keysT region (fp32).
// ---------------------------------------------------------------------------
__global__ __launch_bounds__(256)
void keys_k(float* __restrict__ out, const float* __restrict__ W1,
            const float* __restrict__ b1)
{
    __shared__ __align__(16) float As[16 * 512];
    const int tid = threadIdx.x;
    const int r0  = blockIdx.x * 16;

    #pragma unroll
    for (int i = 0; i < 32; ++i) {
        const int idx = tid + i * 256;
        const int r = idx >> 9, k = idx & 511;
        As[idx] = out[(r0 + r) * 2048 + k];
    }
    __syncthreads();

    const int bb = r0 >> 6;
    const int n1 = tid, n2 = tid + 256;
    float acc1[16], acc2[16];
    const float bb1 = b1[n1], bb2 = b1[n2];
    #pragma unroll
    for (int r = 0; r < 16; ++r) { acc1[r] = bb1; acc2[r] = bb2; }

    for (int k = 0; k < 512; k += 4) {
        float w1[4], w2[4];
        #pragma unroll
        for (int kk = 0; kk < 4; ++kk) {
            w1[kk] = W1[(k + kk) * 512 + n1];
            w2[kk] = W1[(k + kk) * 512 + n2];
        }
        #pragma unroll
        for (int r = 0; r < 16; ++r) {
            const float4 a = *reinterpret_cast<const float4*>(&As[r * 512 + k]);
            acc1[r] += a.x * w1[0] + a.y * w1[1] + a.z * w1[2] + a.w * w1[3];
            acc2[r] += a.x * w2[0] + a.y * w2[1] + a.z * w2[2] + a.w * w2[3];
        }
    }

    #pragma unroll
    for (int r = 0; r < 16; ++r) {
        const int tt = (r0 + r) & 63;
        const int a1 = (bb * 32 + (n1 >> 4)) * 2048 + 1024 + ((n1 & 15) << 6) + tt;
        const int a2 = (bb * 32 + (n2 >> 4)) * 2048 + 1024 + ((n2 & 15) << 6) + tt;
        out[a1] = acc1[r];
        out[a2] = acc2[r];
    }
}

// ---------------------------------------------------------------------------
// EMBX[v,n] = ((emb[v]*g2+beta2) @ Wxd_bot)[n] + (beta1 @ Wxd_top)[n] + bx_d[n]
// -> bf16 at row 8192+v, bf16 offset (8192+v)*4096 + 2048 + n. grid (128,3).
// ---------------------------------------------------------------------------
__global__ __launch_bounds__(256)
void embx_k(float* __restrict__ out, const float* __restrict__ emb,
            const float* __restrict__ g, const float* __restrict__ be,
            const float* __restrict__ Wxd, const float* __restrict__ bxd)
{
    __shared__ __align__(16) float As[16 * 512];
    const int tid = threadIdx.x;
    const int r0  = blockIdx.x * 16;
    const int n0  = blockIdx.y * 512;

    #pragma unroll
    for (int i = 0; i < 32; ++i) {
        const int idx = tid + i * 256;
        const int r = idx >> 9, k = idx & 511;
        As[idx] = emb[(r0 + r) * 512 + k] * (g[512 + k] * INV_SQ) + be[512 + k];
    }
    __syncthreads();

    const int n1 = n0 + tid, n2 = n0 + tid + 256;
    float cv1 = bxd[n1], cv2 = bxd[n2];
    for (int i = 0; i < 512; ++i) {
        const float bi = be[i];
        cv1 += bi * Wxd[i * 1536 + n1];
        cv2 += bi * Wxd[i * 1536 + n2];
    }

    float acc1[16], acc2[16];
    #pragma unroll
    for (int r = 0; r < 16; ++r) { acc1[r] = cv1; acc2[r] = cv2; }

    for (int k = 0; k < 512; k += 4) {
        float w1[4], w2[4];
        #pragma unroll
        for (int kk = 0; kk < 4; ++kk) {
            w1[kk] = Wxd[(512 + k + kk) * 1536 + n1];
            w2[kk] = Wxd[(512 + k + kk) * 1536 + n2];
        }
        #pragma unroll
        for (int r = 0; r < 16; ++r) {
            const float4 a = *reinterpret_cast<const float4*>(&As[r * 512 + k]);
            acc1[r] += a.x * w1[0] + a.y * w1[1] + a.z * w1[2] + a.w * w1[3];
            acc2[r] += a.x * w2[0] + a.y * w2[1] + a.z * w2[2] + a.w * w2[3];
        }
    }

    bf16* obf = (bf16*)out;
    #pragma unroll
    for (int r = 0; r < 16; ++r) {
        const size_t base = (size_t)(8192 + r0 + r) * 4096 + 2048;
        obf[base + n1] = __float2bfloat16(acc1[r]);
        obf[base + n2] = __float2bfloat16(acc2[r]);
    }
}

// ---------------------------------------------------------------------------
// Repack W2 and Wxd_top into bf16 ushort8 tiles inside d_out.
//   W2p  flat w = k8*4096 + c*8 + j  = W2[(k8*8+j)*512 + c]       (262144)
//   Wxdp flat x = g*262144 + u8*4096 + c*8 + j = Wxd[(u8*8+j)*1536 + g*512 + c]
// phys bf16 addr: W2p  -> (10240 + w>>11)*4096 + 2048 + (w&2047)
//                 Wxdp -> (10496 + x>>11)*4096 + 2048 + (x&2047)
// ---------------------------------------------------------------------------
__global__ __launch_bounds__(512)
void repack_k(float* __restrict__ out, const float* __restrict__ W2,
              const float* __restrict__ Wxd)
{
    bf16* obf = (bf16*)out;
    const int id = blockIdx.x * 512 + threadIdx.x;   // grid 2048 -> 1,048,576
    if (id < 262144) {
        const int k8 = id >> 12, rem = id & 4095, c = rem >> 3, j = rem & 7;
        const float v = W2[(k8 * 8 + j) * 512 + c];
        obf[(size_t)(10240 + (id >> 11)) * 4096 + 2048 + (id & 2047)] = __float2bfloat16(v);
    } else {
        const int x = id - 262144;
        const int g = x >> 18, rem2 = x & 262143;
        const int u8 = rem2 >> 12, rem = rem2 & 4095, c = rem >> 3, j = rem & 7;
        const float v = Wxd[(u8 * 8 + j) * 1536 + g * 512 + c];
        obf[(size_t)(10496 + (x >> 11)) * 4096 + 2048 + (x & 2047)] = __float2bfloat16(v);
    }
}

// ---------------------------------------------------------------------------
// Decoder: persistent per-batch, 512 threads (1 col/thread, 8 waves/CU).
// keysT + enc staged to LDS (bf16) once; in-loop weights from packed bf16
// regions (16B/lane loads, L2-resident: W2p 0.5 MB + Wxdp 1.5 MB shared).
// ---------------------------------------------------------------------------
__global__ __launch_bounds__(512)
void decoder(float* __restrict__ out,
             const float* __restrict__ g1, const float* __restrict__ b2,
             const float* __restrict__ V, const float* __restrict__ bV,
             const float* __restrict__ bh_d, const int* __restrict__ targ)
{
    const int b = blockIdx.x, tid = threadIdx.x;   // 512 threads
    __shared__ bf16  keysL[32768];                 // [n][tt] 64 KiB
    __shared__ bf16  encL[32768];                  // [t][c]  64 KiB
    __shared__ float hs[512], qs[512], cg[512], Vl[512];
    __shared__ float part[8][64], sc[64], wv[64];

    float* erow = out + (size_t)b * 131072;        // 64 rows * 2048
    const bf16* obf = (const bf16*)out;

    for (int i = tid; i < 32768; i += 512) {
        encL[i] = __float2bfloat16(erow[((i >> 9) << 11) + (i & 511)]);
        const int K = b * 32768 + i;
        keysL[i] = __float2bfloat16(out[(K >> 10) * 2048 + 1024 + (K & 1023)]);
    }
    // dec_h0 = concat(forward final (t=63, cols<256), backward final (t=0, cols>=256))
    hs[tid] = (tid < 256) ? erow[63 * 2048 + tid] : erow[tid];
    Vl[tid] = V[tid];
    const float g1c = g1[tid] * INV_SQ;
    const float b2c = b2[tid];
    const float bhz = bh_d[tid], bhr = bh_d[512 + tid], bhn = bh_d[1024 + tid];
    const float bVv = bV[0];
    // per-thread packed-weight base offsets (bf16 elements)
    const int lo = tid & 255, hi = tid >> 8;
    const size_t w2base  = (size_t)(10240 + hi) * 4096 + 2048 + lo * 8;
    const size_t wxbase0 = (size_t)(10496 +       hi) * 4096 + 2048 + lo * 8;
    const size_t wxbase1 = (size_t)(10496 + 128 + hi) * 4096 + 2048 + lo * 8;
    const size_t wxbase2 = (size_t)(10496 + 256 + hi) * 4096 + 2048 + lo * 8;
    __syncthreads();

    for (int t = 0; t < 64; ++t) {
        // ---- q[c] = hs @ W2 + b2
        {
            float a = b2c;
            #pragma unroll 4
            for (int k8 = 0; k8 < 64; ++k8) {
                const us8 w = *reinterpret_cast<const us8*>(obf + w2base + (size_t)k8 * 8192);
                const float* hk = &hs[k8 * 8];
                a += us2f(w[0]) * hk[0] + us2f(w[1]) * hk[1]
                   + us2f(w[2]) * hk[2] + us2f(w[3]) * hk[3]
                   + us2f(w[4]) * hk[4] + us2f(w[5]) * hk[5]
                   + us2f(w[6]) * hk[6] + us2f(w[7]) * hk[7];
            }
            qs[tid] = a;
        }
        __syncthreads();
        // ---- score partials: thread = (group tq of 64 n's, time tt)
        {
            const int tt = tid & 63, tq = tid >> 6;
            float p = 0.0f;
            #pragma unroll 4
            for (int n = tq * 64; n < tq * 64 + 64; ++n) {
                float xx = bf2f(keysL[n * 64 + tt]) + qs[n];
                xx = fminf(fmaxf(xx, -20.0f), 20.0f);
                const float e = __expf(2.0f * xx);      // fast tanh
                p += (e - 1.0f) / (e + 1.0f) * Vl[n];
            }
            part[tq][tt] = p;
        }
        __syncthreads();
        if (tid < 64)
            sc[tid] = part[0][tid] + part[1][tid] + part[2][tid] + part[3][tid]
                    + part[4][tid] + part[5][tid] + part[6][tid] + part[7][tid] + bVv;
        __syncthreads();
        if (tid < 64) {
            float m = -1e30f;
            for (int j = 0; j < 64; ++j) m = fmaxf(m, sc[j]);
            wv[tid] = __expf(sc[tid] - m);
        }
        __syncthreads();
        float s = 0.0f;
        for (int j = 0; j < 64; ++j) s += wv[j];
        const float inv = 1.0f / s;
        // ---- cg[c] = ctx * g1 * INV_SQ
        {
            float a = 0.0f;
            #pragma unroll 4
            for (int j = 0; j < 64; ++j)
                a += wv[j] * bf2f(encL[j * 512 + tid]);
            cg[tid] = a * inv * g1c;
        }
        __syncthreads();
        // ---- xp = EMBX[tok] + cg @ Wxd_top ; gates (h_prev = 0) -> h
        const int tok = targ[b * 64 + t];
        const size_t eb = (size_t)(8192 + tok) * 4096 + 2048;
        float xz = bf2f(obf[eb + tid]);
        float xr = bf2f(obf[eb + 512 + tid]);
        float xh = bf2f(obf[eb + 1024 + tid]);
        #pragma unroll 2
        for (int u8 = 0; u8 < 64; ++u8) {
            const us8 wz = *reinterpret_cast<const us8*>(obf + wxbase0 + (size_t)u8 * 8192);
            const us8 wr = *reinterpret_cast<const us8*>(obf + wxbase1 + (size_t)u8 * 8192);
            const us8 wn = *reinterpret_cast<const us8*>(obf + wxbase2 + (size_t)u8 * 8192);
            const float* cu = &cg[u8 * 8];
            #pragma unroll
            for (int j = 0; j < 8; ++j) {
                xz += us2f(wz[j]) * cu[j];
                xr += us2f(wr[j]) * cu[j];
                xh += us2f(wn[j]) * cu[j];
            }
        }
        const float z = sigm(xz + bhz), r = sigm(xr + bhr);
        const float h = (1.0f - z) * tanhf(xh + r * bhn);
        hs[tid] = h;
        erow[t * 2048 + tid] = h;
        __syncthreads();
    }
}

// ---------------------------------------------------------------------------
// logits = h @ Wfc + bfc, in place: block owns 16 FULL out rows.
// ---------------------------------------------------------------------------
__global__ __launch_bounds__(256)
void logits_k(float* __restrict__ out, const float* __restrict__ Wfc,
              const float* __restrict__ bfc)
{
    __shared__ __align__(16) float hsL[16 * 512];
    const int tid = threadIdx.x;
    const int r0  = blockIdx.x * 16;

    #pragma unroll
    for (int i = 0; i < 32; ++i) {
        const int idx = tid + i * 256;
        const int r = idx >> 9, k = idx & 511;
        hsL[idx] = out[(r0 + r) * 2048 + k];
    }
    __syncthreads();  // all reads of own rows complete before any write below

    for (int half = 0; half < 2; ++half) {
        const int cb = half * 1024 + tid;
        float acc[16][4];
        #pragma unroll
        for (int r = 0; r < 16; ++r)
            #pragma unroll
            for (int j = 0; j < 4; ++j) acc[r][j] = 0.0f;

        for (int k = 0; k < 512; k += 4) {
            float w[4][4];
            #pragma unroll
            for (int kk = 0; kk < 4; ++kk)
                #pragma unroll
                for (int j = 0; j < 4; ++j)
                    w[kk][j] = Wfc[(k + kk) * 2048 + cb + (j << 8)];
            #pragma unroll
            for (int r = 0; r < 16; ++r) {
                const float4 a = *reinterpret_cast<const float4*>(&hsL[r * 512 + k]);
                #pragma unroll
                for (int j = 0; j < 4; ++j)
                    acc[r][j] += a.x * w[0][j] + a.y * w[1][j] + a.z * w[2][j] + a.w * w[3][j];
            }
        }
        float bb[4];
        #pragma unroll
        for (int j = 0; j < 4; ++j) bb[j] = bfc[cb + (j << 8)];
        #pragma unroll
        for (int r = 0; r < 16; ++r)
            #pragma unroll
            for (int j = 0; j < 4; ++j)
                out[(r0 + r) * 2048 + cb + (j << 8)] = acc[r][j] + bb[j];
    }
}

// ---------------------------------------------------------------------------
extern "C" void kernel_launch(void* const* d_in, const int* in_sizes, int n_in,
                              void* d_out, int out_size, void* d_ws, size_t ws_size,
                              hipStream_t stream) {
    (void)in_sizes; (void)n_in; (void)out_size; (void)d_ws; (void)ws_size;
    const float* enc_input = (const float*)d_in[0];
    const float* bn_e_g    = (const float*)d_in[1];
    const float* bn_e_b    = (const float*)d_in[2];
    const float* Wx_f      = (const float*)d_in[3];
    const float* Wh_f      = (const float*)d_in[4];
    const float* bx_f      = (const float*)d_in[5];
    const float* bh_f      = (const float*)d_in[6];
    const float* Wx_b      = (const float*)d_in[7];
    const float* Wh_b      = (const float*)d_in[8];
    const float* bx_b      = (const float*)d_in[9];
    const float* bh_b      = (const float*)d_in[10];
    const float* W1        = (const float*)d_in[11];
    const float* b1        = (const float*)d_in[12];
    const float* W2        = (const float*)d_in[13];
    const float* b2        = (const float*)d_in[14];
    const float* V         = (const float*)d_in[15];
    const float* bV        = (const float*)d_in[16];
    const float* emb       = (const float*)d_in[17];
    const float* bn_d_g    = (const float*)d_in[18];
    const float* bn_d_b    = (const float*)d_in[19];
    const float* Wx_d      = (const float*)d_in[20];
    // d_in[21] = Wh_d unused (decoder GRU runs with h_prev = 0)
    const float* bx_d      = (const float*)d_in[22];
    const float* bh_d      = (const float*)d_in[23];
    const float* Wfc       = (const float*)d_in[24];
    const float* bfc       = (const float*)d_in[25];
    const int*   targ      = (const int*)d_in[26];

    float* out = (float*)d_out;

    // 1. encoder -> enc slots (cols 0..511)
    enc_gru<<<dim3(256), dim3(256), 0, stream>>>(
        enc_input, bn_e_g, bn_e_b, Wx_f, Wh_f, bx_f, bh_f,
        Wx_b, Wh_b, bx_b, bh_b, out);
    // 2. attention keys -> keysT region (fp32)
    keys_k<<<dim3(1024), dim3(256), 0, stream>>>(out, W1, b1);
    // 3. token table -> EMBX bf16 region (rows 8192..10239)
    embx_k<<<dim3(128, 3), dim3(256), 0, stream>>>(out, emb, bn_d_g, bn_d_b, Wx_d, bx_d);
    // 4. pack W2 / Wxd_top to bf16 ushort8 tiles (rows 10240..10879)
    repack_k<<<dim3(2048), dim3(512), 0, stream>>>(out, W2, Wx_d);
    // 5. decoder recurrence: h overwrites enc slots (own rows only)
    decoder<<<dim3(256), dim3(512), 0, stream>>>(
        out, bn_d_g, b2, V, bV, bh_d, targ);
    // 6. logits in place: each block owns 16 full rows
    logits_k<<<dim3(1024), dim3(256), 0, stream>>>(out, Wfc, bfc);
}